// Round 1
// baseline (48.631 us; speedup 1.0000x reference)
//
#include <hip/hip_runtime.h>
#include <hip/hip_bf16.h>

// SpiralConv: out[n][o] = sum_{s,c} x[idx[n][s]][c] * W[o][s*32+c] + b[o]
// N=163842 nodes, SEQ=9, IN_CH=32, OUT_CH=64, fan_in=288.
// Strategy: pre-convert x,W to bf16 (tolerance 1.3e-1 >> bf16 error ~0.05),
// then gather-GEMM with mfma_f32_16x16x32_bf16. One K-step(32) == one
// spiral neighbor (32 channels): A-frag = one 16B load from gathered row,
// B-frag = one 16B load from W row. No LDS.

constexpr int NN   = 163842;
constexpr int SEQ  = 9;
constexpr int INC  = 32;
constexpr int OUTC = 64;
constexpr int FAN  = SEQ * INC;  // 288

using s8    = __attribute__((ext_vector_type(8))) short;   // 8 bf16 = 4 VGPRs
using f32x4 = __attribute__((ext_vector_type(4))) float;

__device__ __forceinline__ unsigned f2bf(float f) {
    union { float f; unsigned u; } c; c.f = f;
    unsigned u = c.u;
    // round-to-nearest-even bf16
    u += 0x7fffu + ((u >> 16) & 1u);
    return (u >> 16) & 0xffffu;
}

// Convert x [NN*INC] and W [OUTC*FAN] fp32 -> bf16 into workspace.
__global__ __launch_bounds__(256) void convert_bf16_kernel(
    const float* __restrict__ x, const float* __restrict__ W,
    unsigned short* __restrict__ xb, unsigned short* __restrict__ wb)
{
    const int xq = NN * INC / 4;    // 1310736 float4s
    const int wq = OUTC * FAN / 4;  // 4608 float4s
    int i = blockIdx.x * blockDim.x + threadIdx.x;
    if (i < xq) {
        float4 v = reinterpret_cast<const float4*>(x)[i];
        unsigned lo = f2bf(v.x) | (f2bf(v.y) << 16);
        unsigned hi = f2bf(v.z) | (f2bf(v.w) << 16);
        reinterpret_cast<uint2*>(xb)[i] = make_uint2(lo, hi);
    } else if (i < xq + wq) {
        int j = i - xq;
        float4 v = reinterpret_cast<const float4*>(W)[j];
        unsigned lo = f2bf(v.x) | (f2bf(v.y) << 16);
        unsigned hi = f2bf(v.z) | (f2bf(v.w) << 16);
        reinterpret_cast<uint2*>(wb)[j] = make_uint2(lo, hi);
    }
}

// Gather-GEMM. Block = 256 threads = 4 waves. Each wave: 32 nodes x 64 outs
// (2 M-frags x 4 N-frags of 16x16). Block covers 128 nodes.
__global__ __launch_bounds__(256) void spiral_gemm_kernel(
    const int* __restrict__ idx,              // [NN][SEQ] int32
    const unsigned short* __restrict__ xb,    // [NN][INC] bf16
    const unsigned short* __restrict__ wb,    // [OUTC][FAN] bf16
    const float* __restrict__ bias,           // [OUTC]
    float* __restrict__ out)                  // [NN][OUTC]
{
    const int lane = threadIdx.x & 63;
    const int wid  = threadIdx.x >> 6;
    const int lc   = lane & 15;        // col-within-16 / A row-within-16
    const int lk   = lane >> 4;        // 0..3
    const int kb   = lk * 8;           // k offset within 32-wide K-step

    const int rowBase = blockIdx.x * 128 + wid * 32;

    f32x4 acc[2][4] = {};

    // A-load rows for the two 16-row groups (clamped for the tail block;
    // out-of-range rows compute garbage but are never stored)
    const int r0 = min(rowBase + lc,      NN - 1);
    const int r1 = min(rowBase + 16 + lc, NN - 1);

    #pragma unroll
    for (int s = 0; s < SEQ; ++s) {
        // B fragments: 8 consecutive f-values of W row o, o = n*16+lc
        s8 bfrag[4];
        #pragma unroll
        for (int n = 0; n < 4; ++n) {
            const int o = n * 16 + lc;
            bfrag[n] = *reinterpret_cast<const s8*>(wb + o * FAN + s * 32 + kb);
        }
        // A fragments: gather 8 consecutive channels of neighbor row
        const int n0 = idx[r0 * SEQ + s];
        const int n1 = idx[r1 * SEQ + s];
        s8 a0 = *reinterpret_cast<const s8*>(xb + n0 * INC + kb);
        s8 a1 = *reinterpret_cast<const s8*>(xb + n1 * INC + kb);
        #pragma unroll
        for (int n = 0; n < 4; ++n) {
            acc[0][n] = __builtin_amdgcn_mfma_f32_16x16x32_bf16(a0, bfrag[n], acc[0][n], 0, 0, 0);
            acc[1][n] = __builtin_amdgcn_mfma_f32_16x16x32_bf16(a1, bfrag[n], acc[1][n], 0, 0, 0);
        }
    }

    // Epilogue: C/D layout col=lane&15, row=(lane>>4)*4+reg  [m89-verified]
    #pragma unroll
    for (int m2 = 0; m2 < 2; ++m2) {
        const int rBase = rowBase + m2 * 16 + lk * 4;
        #pragma unroll
        for (int n = 0; n < 4; ++n) {
            const int o  = n * 16 + lc;
            const float bo = bias[o];
            #pragma unroll
            for (int r = 0; r < 4; ++r) {
                const int row = rBase + r;
                if (row < NN) out[row * OUTC + o] = acc[m2][n][r] + bo;
            }
        }
    }
}

extern "C" void kernel_launch(void* const* d_in, const int* in_sizes, int n_in,
                              void* d_out, int out_size, void* d_ws, size_t ws_size,
                              hipStream_t stream) {
    const float* x    = (const float*)d_in[0];
    const int*   idx  = (const int*)d_in[1];     // int32 per harness convention
    const float* W    = (const float*)d_in[2];
    const float* b    = (const float*)d_in[3];
    float*       out  = (float*)d_out;

    unsigned short* xb = (unsigned short*)d_ws;          // NN*INC bf16 = 10.5 MB
    unsigned short* wb = xb + (size_t)NN * INC;          // OUTC*FAN bf16 = 36 KB

    const int totalq = (NN * INC + OUTC * FAN) / 4;      // 1315344
    convert_bf16_kernel<<<(totalq + 255) / 256, 256, 0, stream>>>(x, W, xb, wb);

    const int nblocks = (NN + 127) / 128;                // 1281
    spiral_gemm_kernel<<<nblocks, 256, 0, stream>>>(idx, xb, wb, b, out);
}

// Round 2
// 47.257 us; speedup vs baseline: 1.0291x; 1.0291x over previous
//
#include <hip/hip_runtime.h>
#include <hip/hip_bf16.h>

// SpiralConv: out[n][o] = sum_{s,c} x[idx[n][s]][c] * W[o][s*32+c] + b[o]
// N=163842, SEQ=9, IN_CH=32, OUT_CH=64, fan_in=288.
// bf16 MFMA gather-GEMM. Round 2: full gather prefetch (pay L2/L3 latency
// once per wave, not 9x) + swapped MFMA operands (A=W, B=gathered X) so the
// epilogue is float4 stores (lane's 4 acc regs = 4 consecutive outs).

constexpr int NN   = 163842;
constexpr int SEQ  = 9;
constexpr int INC  = 32;
constexpr int OUTC = 64;
constexpr int FAN  = SEQ * INC;  // 288

using s8    = __attribute__((ext_vector_type(8))) short;   // 8 bf16 = 4 VGPRs
using f32x4 = __attribute__((ext_vector_type(4))) float;

__device__ __forceinline__ unsigned f2bf(float f) {
    union { float f; unsigned u; } c; c.f = f;
    unsigned u = c.u;
    u += 0x7fffu + ((u >> 16) & 1u);   // RNE
    return (u >> 16) & 0xffffu;
}

// Convert x [NN*INC] and W [OUTC*FAN] fp32 -> bf16 into workspace.
__global__ __launch_bounds__(256) void convert_bf16_kernel(
    const float* __restrict__ x, const float* __restrict__ W,
    unsigned short* __restrict__ xb, unsigned short* __restrict__ wb)
{
    const int xq = NN * INC / 4;
    const int wq = OUTC * FAN / 4;
    int i = blockIdx.x * blockDim.x + threadIdx.x;
    if (i < xq) {
        float4 v = reinterpret_cast<const float4*>(x)[i];
        unsigned lo = f2bf(v.x) | (f2bf(v.y) << 16);
        unsigned hi = f2bf(v.z) | (f2bf(v.w) << 16);
        reinterpret_cast<uint2*>(xb)[i] = make_uint2(lo, hi);
    } else if (i < xq + wq) {
        int j = i - xq;
        float4 v = reinterpret_cast<const float4*>(W)[j];
        unsigned lo = f2bf(v.x) | (f2bf(v.y) << 16);
        unsigned hi = f2bf(v.z) | (f2bf(v.w) << 16);
        reinterpret_cast<uint2*>(wb)[j] = make_uint2(lo, hi);
    }
}

// Gather-GEMM. Block = 256 = 4 waves; wave = 32 nodes x 64 outs.
// A-frag = W row (o = f*16+lc, k consecutive) ; B-frag = gathered x row
// (node = base+lc, k consecutive). D[row=o][col=node]:
// lane's reg r -> o = f*16 + (lane>>4)*4 + r, node = base + (lane&15).
__global__ __launch_bounds__(256) void spiral_gemm_kernel(
    const int* __restrict__ idx,              // [NN][SEQ] int32
    const unsigned short* __restrict__ xb,    // [NN][INC] bf16
    const unsigned short* __restrict__ wb,    // [OUTC][FAN] bf16
    const float* __restrict__ bias,           // [OUTC]
    float* __restrict__ out)                  // [NN][OUTC]
{
    const int lane = threadIdx.x & 63;
    const int wid  = threadIdx.x >> 6;
    const int lc   = lane & 15;
    const int lk   = lane >> 4;
    const int kb   = lk * 8;

    const int nodeBase = blockIdx.x * 128 + wid * 32;

    // Clamped gather rows (tail block: garbage computed, never stored)
    const int r0 = min(nodeBase + lc,      NN - 1);
    const int r1 = min(nodeBase + 16 + lc, NN - 1);

    // ---- Prefetch phase: all indices, then all 18 row-gathers ----
    int n0[SEQ], n1[SEQ];
    #pragma unroll
    for (int s = 0; s < SEQ; ++s) {
        n0[s] = idx[r0 * SEQ + s];
        n1[s] = idx[r1 * SEQ + s];
    }
    s8 xf0[SEQ], xf1[SEQ];
    #pragma unroll
    for (int s = 0; s < SEQ; ++s) {
        xf0[s] = *reinterpret_cast<const s8*>(xb + (size_t)n0[s] * INC + kb);
        xf1[s] = *reinterpret_cast<const s8*>(xb + (size_t)n1[s] * INC + kb);
    }

    // ---- MFMA phase: W frags stream from L1, gathers consumed in order ----
    f32x4 acc[2][4] = {};
    #pragma unroll
    for (int s = 0; s < SEQ; ++s) {
        #pragma unroll
        for (int f = 0; f < 4; ++f) {
            s8 wfrag = *reinterpret_cast<const s8*>(wb + (f * 16 + lc) * FAN + s * 32 + kb);
            acc[0][f] = __builtin_amdgcn_mfma_f32_16x16x32_bf16(wfrag, xf0[s], acc[0][f], 0, 0, 0);
            acc[1][f] = __builtin_amdgcn_mfma_f32_16x16x32_bf16(wfrag, xf1[s], acc[1][f], 0, 0, 0);
        }
    }

    // ---- Epilogue: float4 stores (4 consecutive outs per reg quad) ----
    #pragma unroll
    for (int f = 0; f < 4; ++f) {
        const float4 b4 = *reinterpret_cast<const float4*>(bias + f * 16 + lk * 4);
        #pragma unroll
        for (int m = 0; m < 2; ++m) {
            const int node = nodeBase + m * 16 + lc;
            if (node < NN) {
                float4 v;
                v.x = acc[m][f][0] + b4.x;
                v.y = acc[m][f][1] + b4.y;
                v.z = acc[m][f][2] + b4.z;
                v.w = acc[m][f][3] + b4.w;
                *reinterpret_cast<float4*>(out + (size_t)node * OUTC + f * 16 + lk * 4) = v;
            }
        }
    }
}

extern "C" void kernel_launch(void* const* d_in, const int* in_sizes, int n_in,
                              void* d_out, int out_size, void* d_ws, size_t ws_size,
                              hipStream_t stream) {
    const float* x    = (const float*)d_in[0];
    const int*   idx  = (const int*)d_in[1];
    const float* W    = (const float*)d_in[2];
    const float* b    = (const float*)d_in[3];
    float*       out  = (float*)d_out;

    unsigned short* xb = (unsigned short*)d_ws;          // NN*INC bf16 = 10.5 MB
    unsigned short* wb = xb + (size_t)NN * INC;          // OUTC*FAN bf16 = 36 KB

    const int totalq = (NN * INC + OUTC * FAN) / 4;
    convert_bf16_kernel<<<(totalq + 255) / 256, 256, 0, stream>>>(x, W, xb, wb);

    const int nblocks = (NN + 127) / 128;                // 1281
    spiral_gemm_kernel<<<nblocks, 256, 0, stream>>>(idx, xb, wb, b, out);
}